// Round 1
// baseline (355.315 us; speedup 1.0000x reference)
//
#include <hip/hip_runtime.h>

#define D_FEAT 64

// One wavefront (64 lanes) per edge; lane d handles feature d.
// Gather x[src] coalesced, scatter-add to out[tgt] via f32 atomics.
__global__ __launch_bounds__(256) void MessagePassing_scatter_add(
    const float* __restrict__ x,
    const int* __restrict__ src,
    const int* __restrict__ tgt,
    float* __restrict__ out,
    int n_edges)
{
    const int lane = threadIdx.x & 63;
    const int wave = threadIdx.x >> 6;          // 4 waves per 256-thread block
    const long long e = (long long)blockIdx.x * 4 + wave;
    if (e >= n_edges) return;

    const int s = src[e];
    const int t = tgt[e];
    const float v = x[(long long)s * D_FEAT + lane];
    atomicAdd(&out[(long long)t * D_FEAT + lane], v);
}

extern "C" void kernel_launch(void* const* d_in, const int* in_sizes, int n_in,
                              void* d_out, int out_size, void* d_ws, size_t ws_size,
                              hipStream_t stream)
{
    const float* x   = (const float*)d_in[0];
    const int*   ei  = (const int*)d_in[1];      // [2, E] flat int32
    const int n_edges = in_sizes[1] / 2;
    const int* src = ei;                          // edge_index[0] = source (gather)
    const int* tgt = ei + n_edges;                // edge_index[1] = target (scatter)
    float* out = (float*)d_out;

    // Harness poisons d_out with 0xAA and does not re-poison between replays:
    // zero it every call before accumulating.
    hipMemsetAsync(d_out, 0, (size_t)out_size * sizeof(float), stream);

    const int blocks = (n_edges + 3) / 4;         // 4 edges per 256-thread block
    MessagePassing_scatter_add<<<blocks, 256, 0, stream>>>(x, src, tgt, out, n_edges);
}

// Round 2
// 252.090 us; speedup vs baseline: 1.4095x; 1.4095x over previous
//
#include <hip/hip_runtime.h>

#define D_FEAT 64
#define SCAN_BLOCK 256
#define SCAN_ELEMS 1024   // elements per scan block (4 per thread)

// ---------- fallback: direct atomic scatter-add (verified round 1) ----------
__global__ __launch_bounds__(256) void k_atomic_scatter(
    const float* __restrict__ x, const int* __restrict__ src,
    const int* __restrict__ tgt, float* __restrict__ out, int n_edges)
{
    const int lane = threadIdx.x & 63;
    const int wave = threadIdx.x >> 6;
    const int e = blockIdx.x * 4 + wave;
    if (e >= n_edges) return;
    const float v = x[(long long)src[e] * D_FEAT + lane];
    atomicAdd(&out[(long long)tgt[e] * D_FEAT + lane], v);
}

// ---------- CSR build ----------
__global__ void k_hist(const int* __restrict__ tgt, int* __restrict__ cnt, int E)
{
    int e = blockIdx.x * blockDim.x + threadIdx.x;
    if (e < E) atomicAdd(&cnt[tgt[e]], 1);
}

// per-block exclusive scan over 1024-element chunks; block totals to bsum
__global__ __launch_bounds__(SCAN_BLOCK) void k_scan_partial(
    const int* __restrict__ cnt, int* __restrict__ off,
    int* __restrict__ bsum, int N)
{
    __shared__ int lds[SCAN_BLOCK];
    const int tid = threadIdx.x;
    const int base = blockIdx.x * SCAN_ELEMS + tid * 4;
    int v0 = (base + 0 < N) ? cnt[base + 0] : 0;
    int v1 = (base + 1 < N) ? cnt[base + 1] : 0;
    int v2 = (base + 2 < N) ? cnt[base + 2] : 0;
    int v3 = (base + 3 < N) ? cnt[base + 3] : 0;
    const int tsum = v0 + v1 + v2 + v3;
    int val = tsum;
    lds[tid] = val;
    __syncthreads();
    for (int d = 1; d < SCAN_BLOCK; d <<= 1) {
        int add = (tid >= d) ? lds[tid - d] : 0;
        __syncthreads();
        val += add;
        lds[tid] = val;
        __syncthreads();
    }
    if (tid == SCAN_BLOCK - 1) bsum[blockIdx.x] = val;   // inclusive block total
    int p = val - tsum;                                   // exclusive within block
    if (base + 0 < N) { off[base + 0] = p; p += v0; }
    if (base + 1 < N) { off[base + 1] = p; p += v1; }
    if (base + 2 < N) { off[base + 2] = p; p += v2; }
    if (base + 3 < N) { off[base + 3] = p; p += v3; }
}

// single-block exclusive scan of block sums (nb <= 1024)
__global__ __launch_bounds__(1024) void k_scan_sums(int* __restrict__ bsum, int nb)
{
    __shared__ int lds[1024];
    const int tid = threadIdx.x;
    const int v = (tid < nb) ? bsum[tid] : 0;
    int val = v;
    lds[tid] = val;
    __syncthreads();
    for (int d = 1; d < 1024; d <<= 1) {
        int add = (tid >= d) ? lds[tid - d] : 0;
        __syncthreads();
        val += add;
        lds[tid] = val;
        __syncthreads();
    }
    if (tid < nb) bsum[tid] = val - v;                    // exclusive
}

__global__ void k_scan_add(int* __restrict__ off, int* __restrict__ cur,
                           const int* __restrict__ bsum, int N)
{
    int i = blockIdx.x * blockDim.x + threadIdx.x;
    if (i < N) {
        int o = off[i] + bsum[i / SCAN_ELEMS];
        off[i] = o;
        cur[i] = o;
    }
}

__global__ void k_scatter(const int* __restrict__ src, const int* __restrict__ tgt,
                          int* __restrict__ cur, int* __restrict__ srcSorted, int E)
{
    int e = blockIdx.x * blockDim.x + threadIdx.x;
    if (e < E) {
        int p = atomicAdd(&cur[tgt[e]], 1);
        srcSorted[p] = src[e];
    }
}

// one wave per node: lane d accumulates feature d over the node's in-edges
__global__ __launch_bounds__(256) void k_gather(
    const float* __restrict__ x, const int* __restrict__ srcSorted,
    const int* __restrict__ off, const int* __restrict__ cnt,
    float* __restrict__ out, int N)
{
    const int lane = threadIdx.x & 63;
    const int wave = threadIdx.x >> 6;
    const int v = blockIdx.x * 4 + wave;
    if (v >= N) return;
    const int start = __builtin_amdgcn_readfirstlane(off[v]);
    const int deg   = __builtin_amdgcn_readfirstlane(cnt[v]);
    float acc = 0.f;
    int k = 0;
    for (; k + 4 <= deg; k += 4) {       // 4-way ILP on the gather loads
        int s0 = srcSorted[start + k + 0];
        int s1 = srcSorted[start + k + 1];
        int s2 = srcSorted[start + k + 2];
        int s3 = srcSorted[start + k + 3];
        acc += x[s0 * D_FEAT + lane];
        acc += x[s1 * D_FEAT + lane];
        acc += x[s2 * D_FEAT + lane];
        acc += x[s3 * D_FEAT + lane];
    }
    for (; k < deg; ++k)
        acc += x[srcSorted[start + k] * D_FEAT + lane];
    out[v * D_FEAT + lane] = acc;
}

extern "C" void kernel_launch(void* const* d_in, const int* in_sizes, int n_in,
                              void* d_out, int out_size, void* d_ws, size_t ws_size,
                              hipStream_t stream)
{
    const float* x  = (const float*)d_in[0];
    const int*   ei = (const int*)d_in[1];     // [2, E] flat int32
    const int E = in_sizes[1] / 2;
    const int N = out_size / D_FEAT;
    const int* src = ei;                        // edge_index[0] = source (gather)
    const int* tgt = ei + E;                    // edge_index[1] = target (scatter)
    float* out = (float*)d_out;

    const int nScanBlocks = (N + SCAN_ELEMS - 1) / SCAN_ELEMS;   // 98 for N=100K
    // ws layout (int32): cnt[N] | off[N] | cur[N] | bsum[1024] | srcSorted[E]
    const size_t need = ((size_t)3 * N + 1024 + (size_t)E) * sizeof(int);

    if (ws_size < need || nScanBlocks > 1024) {
        // fallback: verified atomic path
        hipMemsetAsync(d_out, 0, (size_t)out_size * sizeof(float), stream);
        k_atomic_scatter<<<(E + 3) / 4, 256, 0, stream>>>(x, src, tgt, out, E);
        return;
    }

    int* cnt = (int*)d_ws;
    int* off = cnt + N;
    int* cur = off + N;
    int* bsum = cur + N;
    int* srcSorted = bsum + 1024;

    hipMemsetAsync(cnt, 0, (size_t)N * sizeof(int), stream);
    k_hist<<<(E + 255) / 256, 256, 0, stream>>>(tgt, cnt, E);
    k_scan_partial<<<nScanBlocks, SCAN_BLOCK, 0, stream>>>(cnt, off, bsum, N);
    k_scan_sums<<<1, 1024, 0, stream>>>(bsum, nScanBlocks);
    k_scan_add<<<(N + 255) / 256, 256, 0, stream>>>(off, cur, bsum, N);
    k_scatter<<<(E + 255) / 256, 256, 0, stream>>>(src, tgt, cur, srcSorted, E);
    k_gather<<<(N + 3) / 4, 256, 0, stream>>>(x, srcSorted, off, cnt, out, N);
}